// Round 2
// baseline (15.974 us; speedup 1.0000x reference)
//
#include <hip/hip_runtime.h>
#include <math.h>

// Problem constants (from reference)
#define BB    256
#define TT    512
#define D_IN  32
#define EMB   128
#define NOUT  10
#define NQ    4
#define QD    2
#define NTOT  (BB * TT)   // 131072 = 512 blocks * 256 threads exactly

// Fused-weight workspace layout (floats in d_ws):
//   [0..127]   M[j][d]   (4x32)   = w_cip @ w_in
//   [128..167] W2[o][j]  (10x4)   = w_head @ w_coe
//   [168..171] C[j]      (4)      = w_cip @ b_in
//   [172..179] cw[l][w]  (2x4)    = cos(q_weights/2)
//   [180..187] sw[l][w]  (2x4)    = sin(q_weights/2)
#define WS_FLOATS 188

// RX(theta) on the wire whose bit-mask is `mask` (wire w -> mask 8>>w).
__device__ __forceinline__ void apply_rx(float re[16], float im[16],
                                         const int mask, const float c, const float s) {
#pragma unroll
    for (int i = 0; i < 16; ++i) {
        if (i & mask) continue;
        const int j = i | mask;
        const float r0 = re[i], i0 = im[i], r1 = re[j], i1 = im[j];
        re[i] = c * r0 + s * i1;
        im[i] = c * i0 - s * r1;
        re[j] = c * r1 + s * i0;
        im[j] = c * i1 - s * r0;
    }
}

// One-block prep: fuse the linear layers around the quantum circuit.
__global__ __launch_bounds__(256) void qnn_prep_kernel(
    const float* __restrict__ w_in,      // (128,32)
    const float* __restrict__ b_in,      // (128,)
    const float* __restrict__ w_cip,     // (4,128)
    const float* __restrict__ q_weights, // (2,4)
    const float* __restrict__ w_coe,     // (128,4)
    const float* __restrict__ w_head,    // (10,128)
    float* __restrict__ fused)           // WS_FLOATS
{
    const int tid = threadIdx.x;
    if (tid < 128) {
        const int j = tid >> 5, d = tid & 31;
        float acc = 0.f;
#pragma unroll 8
        for (int e = 0; e < EMB; ++e)
            acc += w_cip[j * EMB + e] * w_in[e * D_IN + d];
        fused[tid] = acc;
    } else if (tid < 168) {
        const int k = tid - 128;
        const int o = k >> 2, j = k & 3;
        float acc = 0.f;
#pragma unroll 8
        for (int e = 0; e < EMB; ++e)
            acc += w_head[o * EMB + e] * w_coe[e * NQ + j];
        fused[tid] = acc;
    } else if (tid < 172) {
        const int j = tid - 168;
        float acc = 0.f;
        for (int e = 0; e < EMB; ++e)
            acc += w_cip[j * EMB + e] * b_in[e];
        fused[tid] = acc;
    } else if (tid < 180) {
        const int k = tid - 172;
        const float h = q_weights[k] * 0.5f;
        fused[tid] = cosf(h);       // cw
        fused[tid + 8] = sinf(h);   // sw
    }
}

__global__ __launch_bounds__(256) void qnn_main_kernel(
    const float* __restrict__ inputs,    // (B,T,32)
    const float* __restrict__ fused,     // WS_FLOATS
    float* __restrict__ out)             // (B,T,10)
{
    __shared__ float sF[WS_FLOATS];
    const int tid = threadIdx.x;
    if (tid < WS_FLOATS) sF[tid] = fused[tid];

    const float* sM  = sF;          // 4x32
    const float* sW2 = sF + 128;    // 10x4
    const float* sC  = sF + 168;    // 4
    const float* sCW = sF + 172;    // 2x4
    const float* sSW = sF + 180;    // 2x4

    const int bt = blockIdx.x * 256 + tid;

    // Load one 32-float input row (128 B/thread, float4-vectorized).
    float xin[D_IN];
    const float4* ip = reinterpret_cast<const float4*>(inputs + (size_t)bt * D_IN);
#pragma unroll
    for (int k = 0; k < D_IN / 4; ++k) {
        const float4 v = ip[k];
        xin[k * 4 + 0] = v.x; xin[k * 4 + 1] = v.y;
        xin[k * 4 + 2] = v.z; xin[k * 4 + 3] = v.w;
    }

    __syncthreads();

    // q_in[j] = C[j] + sum_d xin[d] * M[j][d]   (LDS reads are wave-uniform -> broadcast)
    float q[NQ];
#pragma unroll
    for (int j = 0; j < NQ; ++j) {
        float acc = sC[j];
#pragma unroll
        for (int d = 0; d < D_IN; ++d) acc += xin[d] * sM[j * D_IN + d];
        q[j] = acc;
    }

    // 4-qubit statevector in registers. Wire w <-> bit (3-w): mask = 8>>w.
    float re[16], im[16];
#pragma unroll
    for (int i = 0; i < 16; ++i) { re[i] = 0.f; im[i] = 0.f; }
    re[0] = 1.f;

    // AngleEmbedding: RX(q_in[w]) on each wire. Angles are O(0.3) -> fast sincos fine.
#pragma unroll
    for (int w = 0; w < NQ; ++w) {
        float s, c;
        __sincosf(q[w] * 0.5f, &s, &c);
        apply_rx(re, im, 8 >> w, c, s);
    }

    // BasicEntanglerLayers: RX(q_weights[l][w]) then CNOT ring.
#pragma unroll
    for (int l = 0; l < QD; ++l) {
#pragma unroll
        for (int w = 0; w < NQ; ++w)
            apply_rx(re, im, 8 >> w, sCW[l * NQ + w], sSW[l * NQ + w]);
#pragma unroll
        for (int w = 0; w < NQ; ++w) {
            const int cm = 8 >> w;
            const int tm = 8 >> ((w + 1) & 3);
#pragma unroll
            for (int i = 0; i < 16; ++i) {
                if ((i & cm) && !(i & tm)) {
                    const int i2 = i | tm;
                    const float tr = re[i]; re[i] = re[i2]; re[i2] = tr;
                    const float ti = im[i]; im[i] = im[i2]; im[i2] = ti;
                }
            }
        }
    }

    // Probabilities and PauliZ expectation values per wire.
    float p[16];
#pragma unroll
    for (int i = 0; i < 16; ++i) p[i] = re[i] * re[i] + im[i] * im[i];

    float z[NQ];
#pragma unroll
    for (int w = 0; w < NQ; ++w) {
        const int m = 8 >> w;
        float acc = 0.f;
#pragma unroll
        for (int i = 0; i < 16; ++i) acc += (i & m) ? -p[i] : p[i];
        z[w] = acc;
    }

    // preds[o] = sum_j z[j] * W2[o][j]; store as 5x float2 (40B, 8B-aligned).
    float ov[NOUT];
#pragma unroll
    for (int o = 0; o < NOUT; ++o) {
        float acc = 0.f;
#pragma unroll
        for (int j = 0; j < NQ; ++j) acc += z[j] * sW2[o * NQ + j];
        ov[o] = acc;
    }
    float2* op = reinterpret_cast<float2*>(out + (size_t)bt * NOUT);
#pragma unroll
    for (int o = 0; o < NOUT / 2; ++o)
        op[o] = make_float2(ov[2 * o], ov[2 * o + 1]);
}

extern "C" void kernel_launch(void* const* d_in, const int* in_sizes, int n_in,
                              void* d_out, int out_size, void* d_ws, size_t ws_size,
                              hipStream_t stream) {
    const float* inputs    = (const float*)d_in[0];
    const float* w_in      = (const float*)d_in[1];
    const float* b_in      = (const float*)d_in[2];
    const float* w_cip     = (const float*)d_in[3];
    const float* q_weights = (const float*)d_in[4];
    const float* w_coe     = (const float*)d_in[5];
    const float* w_head    = (const float*)d_in[6];
    float* out   = (float*)d_out;
    float* fused = (float*)d_ws;

    qnn_prep_kernel<<<1, 256, 0, stream>>>(w_in, b_in, w_cip, q_weights, w_coe, w_head, fused);
    qnn_main_kernel<<<NTOT / 256, 256, 0, stream>>>(inputs, fused, out);
}

// Round 3
// 15.087 us; speedup vs baseline: 1.0588x; 1.0588x over previous
//
#include <hip/hip_runtime.h>
#include <math.h>

// Problem constants (from reference)
#define BB    256
#define TT    512
#define D_IN  32
#define EMB   128
#define NOUT  10
#define NQ    4
#define QD    2
#define NTOT  (BB * TT)   // 131072 = 512 blocks * 256 threads exactly

// RX(theta) on the wire whose bit-mask is `mask` (wire w -> mask 8>>w).
// new0 = c*a0 - i*s*a1 ; new1 = c*a1 - i*s*a0
__device__ __forceinline__ void apply_rx(float re[16], float im[16],
                                         const int mask, const float c, const float s) {
#pragma unroll
    for (int i = 0; i < 16; ++i) {
        if (i & mask) continue;
        const int j = i | mask;
        const float r0 = re[i], i0 = im[i], r1 = re[j], i1 = im[j];
        re[i] = c * r0 + s * i1;
        im[i] = c * i0 - s * r1;
        re[j] = c * r1 + s * i0;
        im[j] = c * i1 - s * r0;
    }
}

__global__ __launch_bounds__(256) void qnn_fused_kernel(
    const float* __restrict__ inputs,    // (B,T,32)
    const float* __restrict__ w_in,      // (128,32)
    const float* __restrict__ b_in,      // (128,)
    const float* __restrict__ w_cip,     // (4,128)
    const float* __restrict__ q_weights, // (2,4)
    const float* __restrict__ w_coe,     // (128,4)
    const float* __restrict__ w_head,    // (10,128)
    float* __restrict__ out)             // (B,T,10)
{
    // Fused small weights, computed per block (weights are L2-resident).
    __shared__ float sM[NQ * D_IN];   // M[j][d] = sum_e w_cip[j][e]*w_in[e][d]
    __shared__ float sC[NQ];          // c[j] = w_cip@b_in + q_weights[0] folded below
    __shared__ float sW2[NOUT * NQ];  // W2[o][j]= sum_e w_head[o][e]*w_coe[e][j]
    __shared__ float sH0[NQ];         // 0.5 * q_weights[0][w]  (merged into embedding RX)
    __shared__ float sCW[NQ];         // cos(q_weights[1]/2)
    __shared__ float sSW[NQ];         // sin(q_weights[1]/2)

    const int tid = threadIdx.x;
    const int bt = blockIdx.x * 256 + tid;

    // Issue the 128B/thread input load FIRST so HBM latency overlaps the
    // per-block weight fusion below.
    float xin[D_IN];
    const float4* ip = reinterpret_cast<const float4*>(inputs + (size_t)bt * D_IN);
#pragma unroll
    for (int k = 0; k < D_IN / 4; ++k) {
        const float4 v = ip[k];
        xin[k * 4 + 0] = v.x; xin[k * 4 + 1] = v.y;
        xin[k * 4 + 2] = v.z; xin[k * 4 + 3] = v.w;
    }

    if (tid < 128) {
        const int j = tid >> 5, d = tid & 31;
        float acc = 0.f;
#pragma unroll 8
        for (int e = 0; e < EMB; ++e)
            acc += w_cip[j * EMB + e] * w_in[e * D_IN + d];
        sM[tid] = acc;
    } else if (tid < 168) {
        const int k = tid - 128;
        const int o = k >> 2, j = k & 3;
        float acc = 0.f;
#pragma unroll 8
        for (int e = 0; e < EMB; ++e)
            acc += w_head[o * EMB + e] * w_coe[e * NQ + j];
        sW2[k] = acc;
    } else if (tid < 172) {
        const int j = tid - 168;
        float acc = 0.f;
        for (int e = 0; e < EMB; ++e)
            acc += w_cip[j * EMB + e] * b_in[e];
        sC[j] = acc;
    } else if (tid < 176) {
        const int w = tid - 172;
        sH0[w] = 0.5f * q_weights[w];            // layer 0 half-angles
    } else if (tid < 180) {
        const int w = tid - 176;
        const float h = 0.5f * q_weights[NQ + w]; // layer 1
        sCW[w] = cosf(h);
        sSW[w] = sinf(h);
    }
    __syncthreads();

    // q_half[j] = 0.5*(C[j] + sum_d xin[d]*M[j][d]) + 0.5*qw0[j]
    // RX(q)·RX(qw0) on same wire with nothing between = RX(q + qw0).
    float q[NQ];
#pragma unroll
    for (int j = 0; j < NQ; ++j) {
        float acc = sC[j];
#pragma unroll
        for (int d = 0; d < D_IN; ++d) acc += xin[d] * sM[j * D_IN + d];
        q[j] = 0.5f * acc + sH0[j];
    }

    // 4-qubit statevector in registers. Wire w <-> bit (3-w): mask = 8>>w.
    float re[16], im[16];
#pragma unroll
    for (int i = 0; i < 16; ++i) { re[i] = 0.f; im[i] = 0.f; }
    re[0] = 1.f;

    // Merged embedding + layer-0 RX. Angles are O(1) -> fast sincos fine.
#pragma unroll
    for (int w = 0; w < NQ; ++w) {
        float s, c;
        __sincosf(q[w], &s, &c);
        apply_rx(re, im, 8 >> w, c, s);
    }

    // Layer-0 CNOT ring (pure register permutation, free).
#pragma unroll
    for (int w = 0; w < NQ; ++w) {
        const int cm = 8 >> w;
        const int tm = 8 >> ((w + 1) & 3);
#pragma unroll
        for (int i = 0; i < 16; ++i) {
            if ((i & cm) && !(i & tm)) {
                const int i2 = i | tm;
                const float tr = re[i]; re[i] = re[i2]; re[i2] = tr;
                const float ti = im[i]; im[i] = im[i2]; im[i2] = ti;
            }
        }
    }

    // Layer-1 RX (fixed angles) + CNOT ring.
#pragma unroll
    for (int w = 0; w < NQ; ++w)
        apply_rx(re, im, 8 >> w, sCW[w], sSW[w]);
#pragma unroll
    for (int w = 0; w < NQ; ++w) {
        const int cm = 8 >> w;
        const int tm = 8 >> ((w + 1) & 3);
#pragma unroll
        for (int i = 0; i < 16; ++i) {
            if ((i & cm) && !(i & tm)) {
                const int i2 = i | tm;
                const float tr = re[i]; re[i] = re[i2]; re[i2] = tr;
                const float ti = im[i]; im[i] = im[i2]; im[i2] = ti;
            }
        }
    }

    // Probabilities and PauliZ expectation values per wire.
    float p[16];
#pragma unroll
    for (int i = 0; i < 16; ++i) p[i] = re[i] * re[i] + im[i] * im[i];

    float z[NQ];
#pragma unroll
    for (int w = 0; w < NQ; ++w) {
        const int m = 8 >> w;
        float acc = 0.f;
#pragma unroll
        for (int i = 0; i < 16; ++i) acc += (i & m) ? -p[i] : p[i];
        z[w] = acc;
    }

    // preds[o] = sum_j z[j] * W2[o][j]; store as 5x float2 (40B, 8B-aligned).
    float ov[NOUT];
#pragma unroll
    for (int o = 0; o < NOUT; ++o) {
        float acc = 0.f;
#pragma unroll
        for (int j = 0; j < NQ; ++j) acc += z[j] * sW2[o * NQ + j];
        ov[o] = acc;
    }
    float2* op = reinterpret_cast<float2*>(out + (size_t)bt * NOUT);
#pragma unroll
    for (int o = 0; o < NOUT / 2; ++o)
        op[o] = make_float2(ov[2 * o], ov[2 * o + 1]);
}

extern "C" void kernel_launch(void* const* d_in, const int* in_sizes, int n_in,
                              void* d_out, int out_size, void* d_ws, size_t ws_size,
                              hipStream_t stream) {
    const float* inputs    = (const float*)d_in[0];
    const float* w_in      = (const float*)d_in[1];
    const float* b_in      = (const float*)d_in[2];
    const float* w_cip     = (const float*)d_in[3];
    const float* q_weights = (const float*)d_in[4];
    const float* w_coe     = (const float*)d_in[5];
    const float* w_head    = (const float*)d_in[6];
    float* out = (float*)d_out;

    qnn_fused_kernel<<<NTOT / 256, 256, 0, stream>>>(
        inputs, w_in, b_in, w_cip, q_weights, w_coe, w_head, out);
}